// Round 1
// baseline (384.857 us; speedup 1.0000x reference)
//
#include <hip/hip_runtime.h>

// WindowMSA fused kernel for MI355X (gfx950).
// One block = one window (B=4096). 4 waves = 4 heads.
// All matmuls via v_mfma_f32_16x16x32_bf16, fp32 accumulate.

typedef __bf16 bf16_t;
typedef __bf16 bf8v  __attribute__((ext_vector_type(8)));
typedef __bf16 bf4v  __attribute__((ext_vector_type(4)));
typedef float  f4v   __attribute__((ext_vector_type(4)));

#define QK_SCALE 0.17677669529663687f  // 1/sqrt(32)

__device__ __forceinline__ f4v mfma16(bf8v a, bf8v b, f4v c) {
  return __builtin_amdgcn_mfma_f32_16x16x32_bf16(a, b, c, 0, 0, 0);
}

// ---------------- prep: swizzle weights to B-fragment order, build CB ----------------
// wq: [t<24][kt<4][lane<64][j<8]  = bf16(qkv_w[t*16+(l&15)][kt*32+(l>>4)*8+j])
// wp: [t<8 ][kt<4][lane<64][j<8]  = bf16(proj_w[...same...])
// cb: [w<64][h<4][n<64][m<64] fp32 = rel_bias + mask, -1e30 for m>=49, 0 for n>=49
__global__ void prep_kernel(const float* __restrict__ mask,
                            const float* __restrict__ qkv_w,
                            const float* __restrict__ proj_w,
                            const float* __restrict__ bias_table,
                            bf16_t* __restrict__ wq,
                            bf16_t* __restrict__ wp,
                            float* __restrict__ cb) {
  const int stride = gridDim.x * blockDim.x;
  const int tid0 = blockIdx.x * blockDim.x + threadIdx.x;
  for (int i = tid0; i < 24 * 4 * 64 * 8; i += stride) {
    int j = i & 7, l = (i >> 3) & 63, kt = (i >> 9) & 3, t = i >> 11;
    int n = t * 16 + (l & 15), k = kt * 32 + (l >> 4) * 8 + j;
    wq[i] = (bf16_t)qkv_w[n * 128 + k];
  }
  for (int i = tid0; i < 8 * 4 * 64 * 8; i += stride) {
    int j = i & 7, l = (i >> 3) & 63, kt = (i >> 9) & 3, t = i >> 11;
    int n = t * 16 + (l & 15), k = kt * 32 + (l >> 4) * 8 + j;
    wp[i] = (bf16_t)proj_w[n * 128 + k];
  }
  for (int i = tid0; i < 64 * 4 * 64 * 64; i += stride) {
    int m = i & 63, n = (i >> 6) & 63, h = (i >> 12) & 3, w = i >> 14;
    float v;
    if (m >= 49) {
      v = -1e30f;                    // mask out padded key columns
    } else if (n >= 49) {
      v = 0.0f;                      // padded query rows: benign logits
    } else {
      int cn = 13 * (n / 7) + n % 7;
      int mm = 48 - m;
      int cm = 13 * (mm / 7) + mm % 7;
      v = bias_table[(cn + cm) * 4 + h] + mask[(w * 49 + n) * 49 + m];
    }
    cb[i] = v;
  }
}

// ---------------- fused window MSA ----------------
__global__ __launch_bounds__(256, 1) void msa_kernel(
    const float* __restrict__ x,
    const float* __restrict__ qkv_b,
    const float* __restrict__ proj_b,
    const bf16_t* __restrict__ wq,
    const bf16_t* __restrict__ wp,
    const float* __restrict__ cb,
    float* __restrict__ out) {
  // strides padded off power-of-2 to spread LDS banks; rows stay 16B aligned
  __shared__ __align__(16) bf16_t As[64][136];    // x (bf16), later reused as attn-out O
  __shared__ __align__(16) bf16_t Qs[4][64][40];  // q*scale  [h][token][d]
  __shared__ __align__(16) bf16_t Ks[4][64][40];  // k        [h][token][d]
  __shared__ __align__(16) bf16_t Vs[4][32][72];  // v^T      [h][d][token]
  __shared__ __align__(16) bf16_t Ps[4][64][72];  // probs    [h][n][m]

  const int tid = threadIdx.x;
  const int wv  = tid >> 6;   // wave 0..3
  const int ln  = tid & 63;
  const int l16 = ln & 15;
  const int l4  = ln >> 4;    // 0..3
  const int b   = blockIdx.x;
  const int w   = b & 63;     // mask window index

  // ---- Phase 1: x -> As (bf16), zero pad rows 49..63 ----
  {
    const float4* xb = (const float4*)(x + (size_t)b * (49 * 128));
    for (int i = tid; i < 64 * 32; i += 256) {
      int r = i >> 5, c4 = (i & 31) << 2;
      float4 v;
      if (r < 49) v = xb[(r * 128 + c4) >> 2];
      else        v = make_float4(0.f, 0.f, 0.f, 0.f);
      bf4v o = { (bf16_t)v.x, (bf16_t)v.y, (bf16_t)v.z, (bf16_t)v.w };
      *(bf4v*)&As[r][c4] = o;
    }
  }
  __syncthreads();

  // ---- Phase 2: QKV GEMM  (M=64, N=384, K=128); wave handles 6 n-tiles ----
  {
    f4v acc[4][6];
    for (int mt = 0; mt < 4; ++mt)
      for (int nj = 0; nj < 6; ++nj) acc[mt][nj] = (f4v){0.f, 0.f, 0.f, 0.f};
    for (int kt = 0; kt < 4; ++kt) {
      bf8v a[4];
      for (int mt = 0; mt < 4; ++mt)
        a[mt] = *(const bf8v*)&As[mt * 16 + l16][kt * 32 + l4 * 8];
      bf8v bwv[6];
      for (int nj = 0; nj < 6; ++nj) {
        int t = wv * 6 + nj;
        bwv[nj] = *(const bf8v*)(wq + (((t * 4 + kt) * 64 + ln) << 3));
      }
      for (int mt = 0; mt < 4; ++mt)
        for (int nj = 0; nj < 6; ++nj)
          acc[mt][nj] = mfma16(a[mt], bwv[nj], acc[mt][nj]);
    }
    // epilogue: +bias, scatter to Qs/Ks/Vs
    for (int nj = 0; nj < 6; ++nj) {
      int t = wv * 6 + nj;
      int n0 = t * 16 + l16;          // 0..383
      float bias = qkv_b[n0];
      int sect = n0 >> 7;             // 0=q 1=k 2=v (uniform per tile)
      int h = (n0 & 127) >> 5;
      int d = n0 & 31;
      for (int mt = 0; mt < 4; ++mt) {
        int row0 = mt * 16 + l4 * 4;
        if (sect == 0) {
          for (int r = 0; r < 4; ++r)
            Qs[h][row0 + r][d] = (bf16_t)((acc[mt][nj][r] + bias) * QK_SCALE);
        } else if (sect == 1) {
          for (int r = 0; r < 4; ++r)
            Ks[h][row0 + r][d] = (bf16_t)(acc[mt][nj][r] + bias);
        } else {
          bf4v o = { (bf16_t)(acc[mt][nj][0] + bias), (bf16_t)(acc[mt][nj][1] + bias),
                     (bf16_t)(acc[mt][nj][2] + bias), (bf16_t)(acc[mt][nj][3] + bias) };
          *(bf4v*)&Vs[h][d][row0] = o;   // transposed store, 4 consecutive tokens
        }
      }
    }
  }
  __syncthreads();

  // ---- Phase 3: per-head attention (wave wv == head) ----
  {
    const int h = wv;
    // QK^T: M=64(n) x N=64(m), K=32 -> single MFMA k-step
    f4v lg[4][4];
    bf8v qf[4], kf[4];
    for (int mt = 0; mt < 4; ++mt) qf[mt] = *(const bf8v*)&Qs[h][mt * 16 + l16][l4 * 8];
    for (int nt = 0; nt < 4; ++nt) kf[nt] = *(const bf8v*)&Ks[h][nt * 16 + l16][l4 * 8];
    for (int mt = 0; mt < 4; ++mt)
      for (int nt = 0; nt < 4; ++nt)
        lg[mt][nt] = mfma16(qf[mt], kf[nt], (f4v){0.f, 0.f, 0.f, 0.f});

    // + combined bias/mask, softmax over m (cols), store P to LDS
    const float* cbp = cb + (((size_t)w * 4 + h) << 12);
    for (int mt = 0; mt < 4; ++mt) {
      for (int r = 0; r < 4; ++r) {
        int row = mt * 16 + l4 * 4 + r;
        float vals[4];
        float mx = -3.0e38f;
        for (int nt = 0; nt < 4; ++nt) {
          float tv = lg[mt][nt][r] + cbp[(row << 6) + nt * 16 + l16];
          vals[nt] = tv;
          mx = fmaxf(mx, tv);
        }
        for (int off = 1; off < 16; off <<= 1) mx = fmaxf(mx, __shfl_xor(mx, off));
        float s = 0.f;
        for (int nt = 0; nt < 4; ++nt) { vals[nt] = __expf(vals[nt] - mx); s += vals[nt]; }
        for (int off = 1; off < 16; off <<= 1) s += __shfl_xor(s, off);
        float inv = 1.0f / s;
        for (int nt = 0; nt < 4; ++nt)
          Ps[h][row][nt * 16 + l16] = (bf16_t)(vals[nt] * inv);
      }
    }

    // PV as O^T = V^T @ P^T : M=32(d), N=64(n), K=64(m)
    f4v oc[2][4];
    for (int mt = 0; mt < 2; ++mt)
      for (int nt = 0; nt < 4; ++nt) oc[mt][nt] = (f4v){0.f, 0.f, 0.f, 0.f};
    for (int ks = 0; ks < 2; ++ks) {
      bf8v vf[2], pf[4];
      for (int mt = 0; mt < 2; ++mt) vf[mt] = *(const bf8v*)&Vs[h][mt * 16 + l16][ks * 32 + l4 * 8];
      for (int nt = 0; nt < 4; ++nt) pf[nt] = *(const bf8v*)&Ps[h][nt * 16 + l16][ks * 32 + l4 * 8];
      for (int mt = 0; mt < 2; ++mt)
        for (int nt = 0; nt < 4; ++nt)
          oc[mt][nt] = mfma16(vf[mt], pf[nt], oc[mt][nt]);
    }
    // store O[n][h*32+d] into As (reused); regs are 4 consecutive d -> packed 8B write
    for (int mt = 0; mt < 2; ++mt)
      for (int nt = 0; nt < 4; ++nt) {
        bf4v o = { (bf16_t)oc[mt][nt][0], (bf16_t)oc[mt][nt][1],
                   (bf16_t)oc[mt][nt][2], (bf16_t)oc[mt][nt][3] };
        *(bf4v*)&As[nt * 16 + l16][h * 32 + mt * 16 + l4 * 4] = o;
      }
  }
  __syncthreads();

  // ---- Phase 4: proj GEMM (M=64, N=128, K=128); wave handles 2 n-tiles ----
  {
    f4v acc[4][2];
    for (int mt = 0; mt < 4; ++mt)
      for (int nj = 0; nj < 2; ++nj) acc[mt][nj] = (f4v){0.f, 0.f, 0.f, 0.f};
    for (int kt = 0; kt < 4; ++kt) {
      bf8v a[4];
      for (int mt = 0; mt < 4; ++mt)
        a[mt] = *(const bf8v*)&As[mt * 16 + l16][kt * 32 + l4 * 8];
      bf8v bwv[2];
      for (int nj = 0; nj < 2; ++nj) {
        int t = wv * 2 + nj;
        bwv[nj] = *(const bf8v*)(wp + (((t * 4 + kt) * 64 + ln) << 3));
      }
      for (int mt = 0; mt < 4; ++mt)
        for (int nj = 0; nj < 2; ++nj)
          acc[mt][nj] = mfma16(a[mt], bwv[nj], acc[mt][nj]);
    }
    float* ob = out + (size_t)b * (49 * 128);
    for (int nj = 0; nj < 2; ++nj) {
      int c = (wv * 2 + nj) * 16 + l16;
      float pb = proj_b[c];
      for (int mt = 0; mt < 4; ++mt) {
        for (int r = 0; r < 4; ++r) {
          int row = mt * 16 + l4 * 4 + r;
          if (row < 49) ob[row * 128 + c] = acc[mt][nj][r] + pb;
        }
      }
    }
  }
}

extern "C" void kernel_launch(void* const* d_in, const int* in_sizes, int n_in,
                              void* d_out, int out_size, void* d_ws, size_t ws_size,
                              hipStream_t stream) {
  const float* x          = (const float*)d_in[0];
  const float* mask       = (const float*)d_in[1];
  const float* qkv_w      = (const float*)d_in[2];
  const float* qkv_b      = (const float*)d_in[3];
  const float* proj_w     = (const float*)d_in[4];
  const float* proj_b     = (const float*)d_in[5];
  const float* bias_table = (const float*)d_in[6];

  char* ws = (char*)d_ws;
  bf16_t* wq = (bf16_t*)ws;                       // 24*4*64*8 bf16 = 98304 B
  bf16_t* wp = (bf16_t*)(ws + 98304);             // 8*4*64*8 bf16  = 32768 B
  float*  cb = (float*)(ws + 131072);             // 64*4*64*64 f32 = 4 MiB

  prep_kernel<<<1024, 256, 0, stream>>>(mask, qkv_w, proj_w, bias_table, wq, wp, cb);
  msa_kernel<<<4096, 256, 0, stream>>>(x, qkv_b, proj_b, wq, wp, cb, (float*)d_out);
}

// Round 2
// 296.402 us; speedup vs baseline: 1.2984x; 1.2984x over previous
//
#include <hip/hip_runtime.h>

// WindowMSA fused kernel for MI355X (gfx950).
// One block = one window (B=4096). 4 waves = 4 heads.
// All matmuls via v_mfma_f32_16x16x32_bf16, fp32 accumulate.
// R2: LDS cut 113.7K -> 76.8K (P aliases QK storage) => 2 blocks/CU.

typedef __bf16 bf16_t;
typedef __bf16 bf8v  __attribute__((ext_vector_type(8)));
typedef __bf16 bf4v  __attribute__((ext_vector_type(4)));
typedef float  f4v   __attribute__((ext_vector_type(4)));

#define QK_SCALE 0.17677669529663687f  // 1/sqrt(32)

__device__ __forceinline__ f4v mfma16(bf8v a, bf8v b, f4v c) {
  return __builtin_amdgcn_mfma_f32_16x16x32_bf16(a, b, c, 0, 0, 0);
}

// ---------------- prep: swizzle weights to B-fragment order, build CB ----------------
// wq: [t<24][kt<4][lane<64][j<8]  = bf16(qkv_w[t*16+(l&15)][kt*32+(l>>4)*8+j])
// wp: [t<8 ][kt<4][lane<64][j<8]  = bf16(proj_w[...same...])
// cb: [w<64][h<4][n<64][m<64] fp32 = rel_bias + mask, -1e30 for m>=49, 0 for n>=49
__global__ void prep_kernel(const float* __restrict__ mask,
                            const float* __restrict__ qkv_w,
                            const float* __restrict__ proj_w,
                            const float* __restrict__ bias_table,
                            bf16_t* __restrict__ wq,
                            bf16_t* __restrict__ wp,
                            float* __restrict__ cb) {
  const int stride = gridDim.x * blockDim.x;
  const int tid0 = blockIdx.x * blockDim.x + threadIdx.x;
  for (int i = tid0; i < 24 * 4 * 64 * 8; i += stride) {
    int j = i & 7, l = (i >> 3) & 63, kt = (i >> 9) & 3, t = i >> 11;
    int n = t * 16 + (l & 15), k = kt * 32 + (l >> 4) * 8 + j;
    wq[i] = (bf16_t)qkv_w[n * 128 + k];
  }
  for (int i = tid0; i < 8 * 4 * 64 * 8; i += stride) {
    int j = i & 7, l = (i >> 3) & 63, kt = (i >> 9) & 3, t = i >> 11;
    int n = t * 16 + (l & 15), k = kt * 32 + (l >> 4) * 8 + j;
    wp[i] = (bf16_t)proj_w[n * 128 + k];
  }
  for (int i = tid0; i < 64 * 4 * 64 * 64; i += stride) {
    int m = i & 63, n = (i >> 6) & 63, h = (i >> 12) & 3, w = i >> 14;
    float v;
    if (m >= 49) {
      v = -1e30f;                    // mask out padded key columns
    } else if (n >= 49) {
      v = 0.0f;                      // padded query rows: benign logits
    } else {
      int cn = 13 * (n / 7) + n % 7;
      int mm = 48 - m;
      int cm = 13 * (mm / 7) + mm % 7;
      v = bias_table[(cn + cm) * 4 + h] + mask[(w * 49 + n) * 49 + m];
    }
    cb[i] = v;
  }
}

// ---------------- fused window MSA ----------------
__global__ __launch_bounds__(256, 2) void msa_kernel(
    const float* __restrict__ x,
    const float* __restrict__ qkv_b,
    const float* __restrict__ proj_b,
    const bf16_t* __restrict__ wq,
    const bf16_t* __restrict__ wp,
    const float* __restrict__ cb,
    float* __restrict__ out) {
  // strides padded off power-of-2 to spread LDS banks; rows stay 16B aligned
  __shared__ __align__(16) bf16_t As[64][136];       // x (bf16), later reused as attn-out O
  __shared__ __align__(16) bf16_t QK[4][2][64][40];  // [h][0=q*scale,1=k][token][d]; P[h] aliases QK[h]
  __shared__ __align__(16) bf16_t Vs[4][32][72];     // v^T [h][d][token]

  const int tid = threadIdx.x;
  const int wv  = tid >> 6;   // wave 0..3
  const int ln  = tid & 63;
  const int l16 = ln & 15;
  const int l4  = ln >> 4;    // 0..3
  const int b   = blockIdx.x;
  const int w   = b & 63;     // mask window index

  // ---- Phase 1: x -> As (bf16), zero pad rows 49..63 ----
  {
    const float4* xb = (const float4*)(x + (size_t)b * (49 * 128));
    for (int i = tid; i < 64 * 32; i += 256) {
      int r = i >> 5, c4 = (i & 31) << 2;
      float4 v;
      if (r < 49) v = xb[(r * 128 + c4) >> 2];
      else        v = make_float4(0.f, 0.f, 0.f, 0.f);
      bf4v o = { (bf16_t)v.x, (bf16_t)v.y, (bf16_t)v.z, (bf16_t)v.w };
      *(bf4v*)&As[r][c4] = o;
    }
  }
  __syncthreads();

  // ---- Phase 2: QKV GEMM  (M=64, N=384, K=128); wave handles 6 n-tiles ----
  {
    f4v acc[4][6];
    for (int mt = 0; mt < 4; ++mt)
      for (int nj = 0; nj < 6; ++nj) acc[mt][nj] = (f4v){0.f, 0.f, 0.f, 0.f};
    for (int kt = 0; kt < 4; ++kt) {
      bf8v a[4];
      for (int mt = 0; mt < 4; ++mt)
        a[mt] = *(const bf8v*)&As[mt * 16 + l16][kt * 32 + l4 * 8];
      bf8v bwv[6];
      for (int nj = 0; nj < 6; ++nj) {
        int t = wv * 6 + nj;
        bwv[nj] = *(const bf8v*)(wq + (((t * 4 + kt) * 64 + ln) << 3));
      }
      for (int mt = 0; mt < 4; ++mt)
        for (int nj = 0; nj < 6; ++nj)
          acc[mt][nj] = mfma16(a[mt], bwv[nj], acc[mt][nj]);
    }
    // epilogue: +bias, scatter to QK / Vs
    for (int nj = 0; nj < 6; ++nj) {
      int t = wv * 6 + nj;
      int n0 = t * 16 + l16;          // 0..383
      float bias = qkv_b[n0];
      int sect = n0 >> 7;             // 0=q 1=k 2=v (uniform per tile)
      int h = (n0 & 127) >> 5;
      int d = n0 & 31;
      for (int mt = 0; mt < 4; ++mt) {
        int row0 = mt * 16 + l4 * 4;
        if (sect == 0) {
          for (int r = 0; r < 4; ++r)
            QK[h][0][row0 + r][d] = (bf16_t)((acc[mt][nj][r] + bias) * QK_SCALE);
        } else if (sect == 1) {
          for (int r = 0; r < 4; ++r)
            QK[h][1][row0 + r][d] = (bf16_t)(acc[mt][nj][r] + bias);
        } else {
          bf4v o = { (bf16_t)(acc[mt][nj][0] + bias), (bf16_t)(acc[mt][nj][1] + bias),
                     (bf16_t)(acc[mt][nj][2] + bias), (bf16_t)(acc[mt][nj][3] + bias) };
          *(bf4v*)&Vs[h][d][row0] = o;   // transposed store, 4 consecutive tokens
        }
      }
    }
  }
  __syncthreads();

  // ---- Phase 3: per-head attention (wave wv == head) ----
  {
    const int h = wv;
    // QK^T: M=64(n) x N=64(m), K=32 -> single MFMA k-step
    f4v lg[4][4];
    bf8v qf[4], kf[4];
    for (int mt = 0; mt < 4; ++mt) qf[mt] = *(const bf8v*)&QK[h][0][mt * 16 + l16][l4 * 8];
    for (int nt = 0; nt < 4; ++nt) kf[nt] = *(const bf8v*)&QK[h][1][nt * 16 + l16][l4 * 8];
    for (int mt = 0; mt < 4; ++mt)
      for (int nt = 0; nt < 4; ++nt)
        lg[mt][nt] = mfma16(qf[mt], kf[nt], (f4v){0.f, 0.f, 0.f, 0.f});

    // P aliases this head's QK slab (wave-private; DS ops are in-order per wave,
    // and qf/kf were read above before any P write issues).
    bf16_t* Pp = &QK[h][0][0][0];      // viewed as [64][72] bf16 (9216 B <= 10240 B)

    // + combined bias/mask, softmax over m (cols), store P to LDS
    const float* cbp = cb + (((size_t)w * 4 + h) << 12);
    for (int mt = 0; mt < 4; ++mt) {
      for (int r = 0; r < 4; ++r) {
        int row = mt * 16 + l4 * 4 + r;
        float vals[4];
        float mx = -3.0e38f;
        for (int nt = 0; nt < 4; ++nt) {
          float tv = lg[mt][nt][r] + cbp[(row << 6) + nt * 16 + l16];
          vals[nt] = tv;
          mx = fmaxf(mx, tv);
        }
        for (int off = 1; off < 16; off <<= 1) mx = fmaxf(mx, __shfl_xor(mx, off));
        float s = 0.f;
        for (int nt = 0; nt < 4; ++nt) { vals[nt] = __expf(vals[nt] - mx); s += vals[nt]; }
        for (int off = 1; off < 16; off <<= 1) s += __shfl_xor(s, off);
        float inv = 1.0f / s;
        for (int nt = 0; nt < 4; ++nt)
          Pp[row * 72 + nt * 16 + l16] = (bf16_t)(vals[nt] * inv);
      }
    }

    // PV as O^T = V^T @ P^T : M=32(d), N=64(n), K=64(m)
    f4v oc[2][4];
    for (int mt = 0; mt < 2; ++mt)
      for (int nt = 0; nt < 4; ++nt) oc[mt][nt] = (f4v){0.f, 0.f, 0.f, 0.f};
    for (int ks = 0; ks < 2; ++ks) {
      bf8v vf[2], pf[4];
      for (int mt = 0; mt < 2; ++mt) vf[mt] = *(const bf8v*)&Vs[h][mt * 16 + l16][ks * 32 + l4 * 8];
      for (int nt = 0; nt < 4; ++nt) pf[nt] = *(const bf8v*)&Pp[(nt * 16 + l16) * 72 + ks * 32 + l4 * 8];
      for (int mt = 0; mt < 2; ++mt)
        for (int nt = 0; nt < 4; ++nt)
          oc[mt][nt] = mfma16(vf[mt], pf[nt], oc[mt][nt]);
    }
    // store O[n][h*32+d] into As (reused); regs are 4 consecutive d -> packed 8B write
    for (int mt = 0; mt < 2; ++mt)
      for (int nt = 0; nt < 4; ++nt) {
        bf4v o = { (bf16_t)oc[mt][nt][0], (bf16_t)oc[mt][nt][1],
                   (bf16_t)oc[mt][nt][2], (bf16_t)oc[mt][nt][3] };
        *(bf4v*)&As[nt * 16 + l16][h * 32 + mt * 16 + l4 * 4] = o;
      }
  }
  __syncthreads();

  // ---- Phase 4: proj GEMM (M=64, N=128, K=128); wave handles 2 n-tiles ----
  {
    f4v acc[4][2];
    for (int mt = 0; mt < 4; ++mt)
      for (int nj = 0; nj < 2; ++nj) acc[mt][nj] = (f4v){0.f, 0.f, 0.f, 0.f};
    for (int kt = 0; kt < 4; ++kt) {
      bf8v a[4];
      for (int mt = 0; mt < 4; ++mt)
        a[mt] = *(const bf8v*)&As[mt * 16 + l16][kt * 32 + l4 * 8];
      bf8v bwv[2];
      for (int nj = 0; nj < 2; ++nj) {
        int t = wv * 2 + nj;
        bwv[nj] = *(const bf8v*)(wp + (((t * 4 + kt) * 64 + ln) << 3));
      }
      for (int mt = 0; mt < 4; ++mt)
        for (int nj = 0; nj < 2; ++nj)
          acc[mt][nj] = mfma16(a[mt], bwv[nj], acc[mt][nj]);
    }
    float* ob = out + (size_t)b * (49 * 128);
    for (int nj = 0; nj < 2; ++nj) {
      int c = (wv * 2 + nj) * 16 + l16;
      float pb = proj_b[c];
      for (int mt = 0; mt < 4; ++mt) {
        for (int r = 0; r < 4; ++r) {
          int row = mt * 16 + l4 * 4 + r;
          if (row < 49) ob[row * 128 + c] = acc[mt][nj][r] + pb;
        }
      }
    }
  }
}

extern "C" void kernel_launch(void* const* d_in, const int* in_sizes, int n_in,
                              void* d_out, int out_size, void* d_ws, size_t ws_size,
                              hipStream_t stream) {
  const float* x          = (const float*)d_in[0];
  const float* mask       = (const float*)d_in[1];
  const float* qkv_w      = (const float*)d_in[2];
  const float* qkv_b      = (const float*)d_in[3];
  const float* proj_w     = (const float*)d_in[4];
  const float* proj_b     = (const float*)d_in[5];
  const float* bias_table = (const float*)d_in[6];

  char* ws = (char*)d_ws;
  bf16_t* wq = (bf16_t*)ws;                       // 24*4*64*8 bf16 = 98304 B
  bf16_t* wp = (bf16_t*)(ws + 98304);             // 8*4*64*8 bf16  = 32768 B
  float*  cb = (float*)(ws + 131072);             // 64*4*64*64 f32 = 4 MiB

  prep_kernel<<<1024, 256, 0, stream>>>(mask, qkv_w, proj_w, bias_table, wq, wp, cb);
  msa_kernel<<<4096, 256, 0, stream>>>(x, qkv_b, proj_b, wq, wp, cb, (float*)d_out);
}

// Round 3
// 293.598 us; speedup vs baseline: 1.3108x; 1.0096x over previous
//
#include <hip/hip_runtime.h>

// WindowMSA fused kernel for MI355X (gfx950).
// One block = one window (B=4096). 4 waves = 4 heads.
// All matmuls via v_mfma_f32_16x16x32_bf16, fp32 accumulate.
// R2: P aliases QK storage => 76.8K LDS, 2 blocks/CU.
// R3: two-region aliased LDS (54,272 B) => 3 blocks/CU; bias table pre-swizzled
//     to MFMA lane order (float4 loads); max-free clamped softmax.

typedef __bf16 bf16_t;
typedef __bf16 bf8v  __attribute__((ext_vector_type(8)));
typedef __bf16 bf4v  __attribute__((ext_vector_type(4)));
typedef float  f4v   __attribute__((ext_vector_type(4)));

#define QK_SCALE 0.17677669529663687f  // 1/sqrt(32)

__device__ __forceinline__ f4v mfma16(bf8v a, bf8v b, f4v c) {
  return __builtin_amdgcn_mfma_f32_16x16x32_bf16(a, b, c, 0, 0, 0);
}

__device__ __forceinline__ bf8v join8(bf4v lo, bf4v hi) {
  return __builtin_shufflevector(lo, hi, 0, 1, 2, 3, 4, 5, 6, 7);
}

// ---------------- prep: swizzle weights to B-fragment order, build CB ----------------
// wq: [t<24][kt<4][lane<64][j<8]  = bf16(qkv_w[t*16+(l&15)][kt*32+(l>>4)*8+j])
// wp: [t<8 ][kt<4][lane<64][j<8]  = bf16(proj_w[...same...])
// cbs: [w<64][h<4][n<64][l16<16][nt<4] fp32 = bias+mask at m = nt*16+l16
//      (-1e30 for m>=49; 0 for n>=49,m<49) -- MFMA lane order => float4 loads.
__global__ void prep_kernel(const float* __restrict__ mask,
                            const float* __restrict__ qkv_w,
                            const float* __restrict__ proj_w,
                            const float* __restrict__ bias_table,
                            bf16_t* __restrict__ wq,
                            bf16_t* __restrict__ wp,
                            float* __restrict__ cbs) {
  const int stride = gridDim.x * blockDim.x;
  const int tid0 = blockIdx.x * blockDim.x + threadIdx.x;
  for (int i = tid0; i < 24 * 4 * 64 * 8; i += stride) {
    int j = i & 7, l = (i >> 3) & 63, kt = (i >> 9) & 3, t = i >> 11;
    int n = t * 16 + (l & 15), k = kt * 32 + (l >> 4) * 8 + j;
    wq[i] = (bf16_t)qkv_w[n * 128 + k];
  }
  for (int i = tid0; i < 8 * 4 * 64 * 8; i += stride) {
    int j = i & 7, l = (i >> 3) & 63, kt = (i >> 9) & 3, t = i >> 11;
    int n = t * 16 + (l & 15), k = kt * 32 + (l >> 4) * 8 + j;
    wp[i] = (bf16_t)proj_w[n * 128 + k];
  }
  for (int i = tid0; i < 64 * 4 * 64 * 64; i += stride) {
    int j = i & 63;                 // l16*4 + nt
    int l16 = j >> 2, nt = j & 3;
    int m = nt * 16 + l16;
    int n = (i >> 6) & 63, h = (i >> 12) & 3, w = i >> 14;
    float v;
    if (m >= 49) {
      v = -1e30f;                    // mask out padded key columns
    } else if (n >= 49) {
      v = 0.0f;                      // padded query rows: benign logits
    } else {
      int cn = 13 * (n / 7) + n % 7;
      int mm = 48 - m;
      int cm = 13 * (mm / 7) + mm % 7;
      v = bias_table[(cn + cm) * 4 + h] + mask[(w * 49 + n) * 49 + m];
    }
    cbs[i] = v;
  }
}

// ---------------- fused window MSA ----------------
__global__ __launch_bounds__(256, 3) void msa_kernel(
    const float* __restrict__ x,
    const float* __restrict__ qkv_b,
    const float* __restrict__ proj_b,
    const bf16_t* __restrict__ wq,
    const bf16_t* __restrict__ wp,
    const float* __restrict__ cbs,
    float* __restrict__ out) {
  // Region A (17,408 B): x-stage As[64][136]; aliased by V^T[4][32][68] after
  //   the mid-phase-2 barrier (all As reads complete before V writes).
  // Region B (4 x 9,216 B wave-private head slabs):
  //   Q[64][36]+K[64][36]  ->  P[64][72] (alias, in-order per wave)
  //   -> O[64][36] (alias over consumed P, in-order per wave).
  __shared__ __align__(16) bf16_t gA[8704];
  __shared__ __align__(16) bf16_t gB[4][4608];

#define AS(r, c)   gA[(r) * 136 + (c)]
#define VT(h, d, t) gA[((h) * 32 + (d)) * 68 + (t)]
#define QQ(h, r, d) gB[h][(r) * 36 + (d)]
#define KK(h, r, d) gB[h][2304 + (r) * 36 + (d)]
#define PP(h, n, m) gB[h][(n) * 72 + (m)]
#define OV(h, t, d) gB[h][(t) * 36 + (d)]

  const int tid = threadIdx.x;
  const int wv  = tid >> 6;   // wave 0..3
  const int ln  = tid & 63;
  const int l16 = ln & 15;
  const int l4  = ln >> 4;    // 0..3
  const int b   = blockIdx.x;
  const int w   = b & 63;     // mask window index

  // ---- Phase 1: x -> As (bf16), zero pad rows 49..63 ----
  {
    const float4* xb = (const float4*)(x + (size_t)b * (49 * 128));
    for (int i = tid; i < 64 * 32; i += 256) {
      int r = i >> 5, c4 = (i & 31) << 2;
      float4 v;
      if (r < 49) v = xb[(r * 128 + c4) >> 2];
      else        v = make_float4(0.f, 0.f, 0.f, 0.f);
      bf4v o = { (bf16_t)v.x, (bf16_t)v.y, (bf16_t)v.z, (bf16_t)v.w };
      *(bf4v*)&AS(r, c4) = o;
    }
  }
  __syncthreads();

  // ---- Phase 2: QKV GEMM  (M=64, N=384, K=128); wave handles 6 n-tiles ----
  {
    f4v acc[4][6];
    for (int mt = 0; mt < 4; ++mt)
      for (int nj = 0; nj < 6; ++nj) acc[mt][nj] = (f4v){0.f, 0.f, 0.f, 0.f};
    for (int kt = 0; kt < 4; ++kt) {
      bf8v a[4];
      for (int mt = 0; mt < 4; ++mt)
        a[mt] = *(const bf8v*)&AS(mt * 16 + l16, kt * 32 + l4 * 8);
      bf8v bwv[6];
      for (int nj = 0; nj < 6; ++nj) {
        int t = wv * 6 + nj;
        bwv[nj] = *(const bf8v*)(wq + (((t * 4 + kt) * 64 + ln) << 3));
      }
      for (int mt = 0; mt < 4; ++mt)
        for (int nj = 0; nj < 6; ++nj)
          acc[mt][nj] = mfma16(a[mt], bwv[nj], acc[mt][nj]);
    }
    // All As reads done (regs hold everything) -> V^T may alias region A.
    __syncthreads();
    // epilogue: +bias, scatter to Q/K slabs and V^T
    for (int nj = 0; nj < 6; ++nj) {
      int t = wv * 6 + nj;
      int n0 = t * 16 + l16;          // 0..383
      float bias = qkv_b[n0];
      int sect = n0 >> 7;             // 0=q 1=k 2=v (uniform per tile)
      int h = (n0 & 127) >> 5;
      int d = n0 & 31;
      for (int mt = 0; mt < 4; ++mt) {
        int row0 = mt * 16 + l4 * 4;
        if (sect == 0) {
          for (int r = 0; r < 4; ++r)
            QQ(h, row0 + r, d) = (bf16_t)((acc[mt][nj][r] + bias) * QK_SCALE);
        } else if (sect == 1) {
          for (int r = 0; r < 4; ++r)
            KK(h, row0 + r, d) = (bf16_t)(acc[mt][nj][r] + bias);
        } else {
          bf4v o = { (bf16_t)(acc[mt][nj][0] + bias), (bf16_t)(acc[mt][nj][1] + bias),
                     (bf16_t)(acc[mt][nj][2] + bias), (bf16_t)(acc[mt][nj][3] + bias) };
          *(bf4v*)&VT(h, d, row0) = o;   // transposed store, 4 consecutive tokens
        }
      }
    }
  }
  __syncthreads();

  // ---- Phase 3: per-head attention (wave wv == head) ----
  {
    const int h = wv;
    // QK^T: M=64(n) x N=64(m), K=32 -> single MFMA k-step
    f4v lg[4][4];
    bf8v qf[4], kf[4];
    for (int mt = 0; mt < 4; ++mt) {
      bf4v lo = *(const bf4v*)&QQ(h, mt * 16 + l16, l4 * 8);
      bf4v hi = *(const bf4v*)&QQ(h, mt * 16 + l16, l4 * 8 + 4);
      qf[mt] = join8(lo, hi);
    }
    for (int nt = 0; nt < 4; ++nt) {
      bf4v lo = *(const bf4v*)&KK(h, nt * 16 + l16, l4 * 8);
      bf4v hi = *(const bf4v*)&KK(h, nt * 16 + l16, l4 * 8 + 4);
      kf[nt] = join8(lo, hi);
    }
    for (int mt = 0; mt < 4; ++mt)
      for (int nt = 0; nt < 4; ++nt)
        lg[mt][nt] = mfma16(qf[mt], kf[nt], (f4v){0.f, 0.f, 0.f, 0.f});

    // softmax over m: max-free (logits are O(+-3)), clamp at -80 so masked
    // entries vanish and a hypothetical all-masked row degrades to uniform
    // (matching the reference). P overwrites this head's Q/K slab.
    const float* cbp = cbs + ((size_t)(w * 4 + h) << 12);
    for (int mt = 0; mt < 4; ++mt) {
      for (int r = 0; r < 4; ++r) {
        int row = mt * 16 + l4 * 4 + r;
        float4 cbv = *(const float4*)(cbp + (row << 6) + l16 * 4);
        float vals[4];
        vals[0] = __expf(fmaxf(lg[mt][0][r] + cbv.x, -80.f));
        vals[1] = __expf(fmaxf(lg[mt][1][r] + cbv.y, -80.f));
        vals[2] = __expf(fmaxf(lg[mt][2][r] + cbv.z, -80.f));
        vals[3] = __expf(fmaxf(lg[mt][3][r] + cbv.w, -80.f));
        float s = (vals[0] + vals[1]) + (vals[2] + vals[3]);
        for (int off = 1; off < 16; off <<= 1) s += __shfl_xor(s, off);
        float inv = 1.0f / s;
        for (int nt = 0; nt < 4; ++nt)
          PP(h, row, nt * 16 + l16) = (bf16_t)(vals[nt] * inv);
      }
    }

    // PV as O^T = V^T @ P^T : M=32(d), N=64(n), K=64(m)
    f4v oc[2][4];
    for (int mt = 0; mt < 2; ++mt)
      for (int nt = 0; nt < 4; ++nt) oc[mt][nt] = (f4v){0.f, 0.f, 0.f, 0.f};
    for (int ks = 0; ks < 2; ++ks) {
      bf8v vf[2], pf[4];
      for (int mt = 0; mt < 2; ++mt) {
        bf4v lo = *(const bf4v*)&VT(h, mt * 16 + l16, ks * 32 + l4 * 8);
        bf4v hi = *(const bf4v*)&VT(h, mt * 16 + l16, ks * 32 + l4 * 8 + 4);
        vf[mt] = join8(lo, hi);
      }
      for (int nt = 0; nt < 4; ++nt)
        pf[nt] = *(const bf8v*)&PP(h, nt * 16 + l16, ks * 32 + l4 * 8);
      for (int mt = 0; mt < 2; ++mt)
        for (int nt = 0; nt < 4; ++nt)
          oc[mt][nt] = mfma16(vf[mt], pf[nt], oc[mt][nt]);
    }
    // store O[token][d] (head-local cols) into this wave's slab over consumed P
    for (int mt = 0; mt < 2; ++mt)
      for (int nt = 0; nt < 4; ++nt) {
        bf4v o = { (bf16_t)oc[mt][nt][0], (bf16_t)oc[mt][nt][1],
                   (bf16_t)oc[mt][nt][2], (bf16_t)oc[mt][nt][3] };
        *(bf4v*)&OV(h, nt * 16 + l16, mt * 16 + l4 * 4) = o;
      }
  }
  __syncthreads();

  // ---- Phase 4: proj GEMM (M=64, N=128, K=128); wave handles 2 n-tiles ----
  // channels kt*32..kt*32+31 live in head-slab kt (OV), d = l4*8..+7.
  {
    f4v acc[4][2];
    for (int mt = 0; mt < 4; ++mt)
      for (int nj = 0; nj < 2; ++nj) acc[mt][nj] = (f4v){0.f, 0.f, 0.f, 0.f};
    for (int kt = 0; kt < 4; ++kt) {
      bf8v a[4];
      for (int mt = 0; mt < 4; ++mt) {
        bf4v lo = *(const bf4v*)&OV(kt, mt * 16 + l16, l4 * 8);
        bf4v hi = *(const bf4v*)&OV(kt, mt * 16 + l16, l4 * 8 + 4);
        a[mt] = join8(lo, hi);
      }
      bf8v bwv[2];
      for (int nj = 0; nj < 2; ++nj) {
        int t = wv * 2 + nj;
        bwv[nj] = *(const bf8v*)(wp + (((t * 4 + kt) * 64 + ln) << 3));
      }
      for (int mt = 0; mt < 4; ++mt)
        for (int nj = 0; nj < 2; ++nj)
          acc[mt][nj] = mfma16(a[mt], bwv[nj], acc[mt][nj]);
    }
    float* ob = out + (size_t)b * (49 * 128);
    for (int nj = 0; nj < 2; ++nj) {
      int c = (wv * 2 + nj) * 16 + l16;
      float pb = proj_b[c];
      for (int mt = 0; mt < 4; ++mt) {
        for (int r = 0; r < 4; ++r) {
          int row = mt * 16 + l4 * 4 + r;
          if (row < 49) ob[row * 128 + c] = acc[mt][nj][r] + pb;
        }
      }
    }
  }
}

extern "C" void kernel_launch(void* const* d_in, const int* in_sizes, int n_in,
                              void* d_out, int out_size, void* d_ws, size_t ws_size,
                              hipStream_t stream) {
  const float* x          = (const float*)d_in[0];
  const float* mask       = (const float*)d_in[1];
  const float* qkv_w      = (const float*)d_in[2];
  const float* qkv_b      = (const float*)d_in[3];
  const float* proj_w     = (const float*)d_in[4];
  const float* proj_b     = (const float*)d_in[5];
  const float* bias_table = (const float*)d_in[6];

  char* ws = (char*)d_ws;
  bf16_t* wq = (bf16_t*)ws;                       // 24*4*64*8 bf16 = 98304 B
  bf16_t* wp = (bf16_t*)(ws + 98304);             // 8*4*64*8 bf16  = 32768 B
  float*  cbs = (float*)(ws + 131072);            // 64*4*64*64 f32 = 4 MiB

  prep_kernel<<<1024, 256, 0, stream>>>(mask, qkv_w, proj_w, bias_table, wq, wp, cbs);
  msa_kernel<<<4096, 256, 0, stream>>>(x, qkv_b, proj_b, wq, wp, cbs, (float*)d_out);
}